// Round 10
// baseline (512.303 us; speedup 1.0000x reference)
//
#include <hip/hip_runtime.h>
#include <math.h>

#define NB 16
#define SS 2048
#define DQ 128
#define SCALE 0.08838834764831845f  // 1/sqrt(128)

typedef __bf16 bf16x8 __attribute__((ext_vector_type(8)));
typedef unsigned short ushort8_t __attribute__((ext_vector_type(8)));
typedef float floatx4 __attribute__((ext_vector_type(4)));

// fp32 -> bf16 round-to-nearest-even (finite randn inputs; no NaN path)
__device__ __forceinline__ unsigned short f2bf(float x) {
  unsigned int u = __float_as_uint(x);
  u += 0x7fffu + ((u >> 16) & 1u);
  return (unsigned short)(u >> 16);
}
union FragU { ushort8_t u; bf16x8 b; };
__device__ __forceinline__ bf16x8 ld_frag(const unsigned short* p) {
  FragU t; t.u = *(const ushort8_t*)p; return t.b;
}
__device__ __forceinline__ floatx4 mfma16(bf16x8 a, bf16x8 b, floatx4 c) {
  return __builtin_amdgcn_mfma_f32_16x16x32_bf16(a, b, c, 0, 0, 0);
}

// LDS-only barrier: waits DS ops, leaves global loads (vmcnt) IN FLIGHT.
__device__ __forceinline__ void bar_lds() {
  asm volatile("s_waitcnt lgkmcnt(0)\n\ts_barrier" ::: "memory");
}

// d_out scratch layout per batch b (each row = DQ floats):
//   rows 64m..64m+15: replicated Linv strips; rows 16..31: colsum accum.
// d_ws: [0,128Mi) E[b][q][k] bf16 = exp(masked_score).

// ---------------------------------------------------------------------------
__global__ void zero_accum(float* __restrict__ O) {
  float* p = O + (size_t)blockIdx.x * SS * DQ + 16 * DQ;
#pragma unroll
  for (int i = 0; i < 8; ++i) p[threadIdx.x + 256 * i] = 0.f;
}

// ---------------------------------------------------------------------------
// Pass 1 (ROUND-9 VERBATIM — best measured: 2 K-tiles resident, 32 MFMA per
// barrier pair). grid (16 kpairs, NB, 4 qchunks) = 1024 blocks, 3/CU.
// ---------------------------------------------------------------------------
template<int WRITE_E>
__global__ __launch_bounds__(256, 3) void pass1_colsum(
    const float* __restrict__ Q, const float* __restrict__ K,
    const int* __restrict__ M, float* __restrict__ O,
    unsigned short* __restrict__ E)
{
  const int k0  = blockIdx.x * 128;       // two 64-wide k-tiles
  const int b   = blockIdx.y;
  const int qc  = blockIdx.z;
  const int tid = threadIdx.x;
  const int w = tid >> 6, lane = tid & 63, l15 = lane & 15, quad = lane >> 4;

  __shared__ unsigned short Kbf[128][136];  // 34.8 KB (resident, 2 tiles)
  __shared__ unsigned short Qbf[64][136];   // 17.4 KB (per q-iter; reduction
                                            //  buffer aliases here at the end)

  const float* Qb = Q + (size_t)b * SS * DQ;
  const float* Kb = K + (size_t)b * SS * DQ;
  const int*   Mb = M + (size_t)b * SS * SS;
  unsigned short* Eb = WRITE_E ? (E + (size_t)b * SS * SS) : nullptr;

  const int srow = tid >> 5;              // staging row base (this thread)
  const int sc4  = (tid & 31) * 4;        // staging col (floats)

  // stage K strip 128 x 128 -> bf16 (resident, both tiles)
#pragma unroll
  for (int r = 0; r < 16; ++r) {
    int row = srow + r * 8;
    float4 v = *(const float4*)(Kb + (size_t)(k0 + row) * DQ + sc4);
    *(ushort4*)&Kbf[row][sc4] = make_ushort4(f2bf(v.x), f2bf(v.y), f2bf(v.z), f2bf(v.w));
  }

  const int qlane = 16 * w + l15;         // wave-local q row within iter tile

  // prologue: prefetch q-tile 0 + its mask (both k-tiles) into registers
  float4 qreg[8];
  int4 mv_nxt[8];
  {
    const int q0 = qc * 512;
#pragma unroll
    for (int r = 0; r < 8; ++r)
      qreg[r] = *(const float4*)(Qb + (size_t)(q0 + srow + r * 8) * DQ + sc4);
#pragma unroll
    for (int t2 = 0; t2 < 2; ++t2)
#pragma unroll
      for (int i = 0; i < 4; ++i)
        mv_nxt[t2 * 4 + i] = *(const int4*)(Mb + (size_t)(q0 + qlane) * SS +
                                            k0 + t2 * 64 + 16 * i + quad * 4);
  }

  float colacc[32];
#pragma unroll
  for (int t = 0; t < 32; ++t) colacc[t] = 0.f;

  for (int qi = 0; qi < 8; ++qi) {
    bar_lds();  // prev Qbf readers done (1st iter: K-staging ds_writes drained)
    int4 mv[8];
#pragma unroll
    for (int t = 0; t < 8; ++t) mv[t] = mv_nxt[t];
    // store prefetched Q regs -> LDS (vmcnt waits are fine-grained here)
#pragma unroll
    for (int r = 0; r < 8; ++r) {
      float4 v = qreg[r];
      *(ushort4*)&Qbf[srow + r * 8][sc4] =
          make_ushort4(f2bf(v.x), f2bf(v.y), f2bf(v.z), f2bf(v.w));
    }
    bar_lds();  // Qbf ready; prefetch below flies across the next barrier
    if (qi < 7) {
      const int qn = qc * 512 + (qi + 1) * 64;
#pragma unroll
      for (int r = 0; r < 8; ++r)
        qreg[r] = *(const float4*)(Qb + (size_t)(qn + srow + r * 8) * DQ + sc4);
#pragma unroll
      for (int t2 = 0; t2 < 2; ++t2)
#pragma unroll
        for (int i = 0; i < 4; ++i)
          mv_nxt[t2 * 4 + i] = *(const int4*)(Mb + (size_t)(qn + qlane) * SS +
                                              k0 + t2 * 64 + 16 * i + quad * 4);
    }

    // QK against BOTH k-tiles: 32 MFMAs per barrier pair.
    floatx4 acc[8];
#pragma unroll
    for (int i = 0; i < 8; ++i) acc[i] = (floatx4){0.f, 0.f, 0.f, 0.f};
#pragma unroll
    for (int d0 = 0; d0 < DQ; d0 += 32) {
      bf16x8 bq = ld_frag(&Qbf[qlane][d0 + quad * 8]);
#pragma unroll
      for (int i = 0; i < 4; ++i) {
        bf16x8 ak0 = ld_frag(&Kbf[16 * i + l15][d0 + quad * 8]);
        acc[i] = mfma16(ak0, bq, acc[i]);
        bf16x8 ak1 = ld_frag(&Kbf[64 + 16 * i + l15][d0 + quad * 8]);
        acc[4 + i] = mfma16(ak1, bq, acc[4 + i]);
      }
    }
    // epilogue per k-tile: mask+exp, colsum accum, E write (round-1 math)
    const int qrow = qc * 512 + qi * 64 + qlane;
#pragma unroll
    for (int t2 = 0; t2 < 2; ++t2) {
#pragma unroll
      for (int i = 0; i < 4; ++i) {
        int4 mvw = mv[t2 * 4 + i];
        int mm[4] = {mvw.x, mvw.y, mvw.z, mvw.w};
        float ev[4];
#pragma unroll
        for (int r = 0; r < 4; ++r) {
          float s = mm[r] ? 1e-9f : acc[t2 * 4 + i][r] * SCALE;
          ev[r] = __expf(s);
          colacc[t2 * 16 + i * 4 + r] += ev[r];
        }
        if (WRITE_E) {
          *(ushort4*)(Eb + (size_t)qrow * SS + k0 + t2 * 64 + 16 * i + quad * 4) =
              make_ushort4(f2bf(ev[0]), f2bf(ev[1]), f2bf(ev[2]), f2bf(ev[3]));
        }
      }
    }
  }

  // reduce over the 16 q-lanes (l15 dimension)
#pragma unroll
  for (int t = 0; t < 32; ++t) {
    colacc[t] += __shfl_xor(colacc[t], 1, 64);
    colacc[t] += __shfl_xor(colacc[t], 2, 64);
    colacc[t] += __shfl_xor(colacc[t], 4, 64);
    colacc[t] += __shfl_xor(colacc[t], 8, 64);
  }
  bar_lds();   // all waves done reading Qbf -> safe to alias reduction buffer
  float* red = (float*)&Qbf[0][0];   // 4 x 128 floats = 2 KB, aliased on Qbf
  if (l15 == 0) {
#pragma unroll
    for (int t2 = 0; t2 < 2; ++t2)
#pragma unroll
      for (int i = 0; i < 4; ++i)
#pragma unroll
        for (int r = 0; r < 4; ++r)
          red[w * 128 + t2 * 64 + 16 * i + quad * 4 + r] =
              colacc[t2 * 16 + i * 4 + r];
  }
  bar_lds();
  if (tid < 128) {
    float s = red[tid] + red[128 + tid] + red[256 + tid] + red[384 + tid];
    atomicAdd(O + (size_t)b * SS * DQ + 16 * DQ + k0 + tid, s);
  }
}

// ---------------------------------------------------------------------------
// Combine: inv = 1/colsum; write replicated strips. grid (NB, 8), 256 thr.
// ---------------------------------------------------------------------------
__global__ void combine_linv(float* __restrict__ O) {
  const int b  = blockIdx.x;
  const int jb = blockIdx.y * 4;
  float* Ob = O + (size_t)b * SS * DQ;
#pragma unroll
  for (int it = 0; it < 8; ++it) {
    int k = threadIdx.x + 256 * it;
    float inv = 1.0f / Ob[16 * DQ + k];
#pragma unroll
    for (int j = 0; j < 4; ++j)
      Ob[(size_t)(64 * (jb + j)) * DQ + k] = inv;
  }
}

// ---------------------------------------------------------------------------
// Pass 2 (E-path, DOUBLE-BUFFERED Wt): O[q][d] = sum_k E[q][k]*Linv[k]*V[k][d]
// grid (32, NB) = 512 blocks, 256 thr. ONE barrier per k-tile (round-1 had
// two), and the MFMA phase reads buf[cur] (written LAST iteration) so it no
// longer serially depends on this iteration's staging writes. Schedule per
// iter: bar -> MFMA(buf[cur]) -> stage tile i+1 into buf[cur^1] -> issue
// global prefetch of tile i+2. Writes to buf[cur^1] are ordered against
// iter i-1's readers of that buffer by the barrier (bar_lds = lgkmcnt(0)
// + s_barrier drains each wave's DS ops first).
// ---------------------------------------------------------------------------
__global__ __launch_bounds__(256, 2) void pass2_pv(
    const float* __restrict__ V, const unsigned short* __restrict__ E,
    float* __restrict__ O)
{
  const int b = blockIdx.y, q0 = blockIdx.x * 64;
  const int tid = threadIdx.x;
  const int w = tid >> 6, lane = tid & 63, l15 = lane & 15, quad = lane >> 4;

  __shared__ unsigned short Wt[2][128][72];  // 36.9 KB  [buf][d][k^swz]
  __shared__ float Li[SS];                   //  8.0 KB

  const float* Vb = V + (size_t)b * SS * DQ;
  const unsigned short* Erow =
      E + (size_t)b * SS * SS + (size_t)(q0 + 16 * w + l15) * SS;

  const int sc4 = (tid & 31) * 4;
  const int vk2 = (tid >> 5) * 2;   // V row-pair base for this thread (0..14)

  // preload replicated Linv strip from own territory (before any O write)
  {
    const float* src = O + ((size_t)b * SS + q0) * DQ;
#pragma unroll
    for (int r = 0; r < 2; ++r) {
      int idx = (tid + r * 256) * 4;
      *(float4*)&Li[idx] = *(const float4*)(src + idx);
    }
  }

  floatx4 accO[8];
#pragma unroll
  for (int j = 0; j < 8; ++j) accO[j] = (floatx4){0.f, 0.f, 0.f, 0.f};

  // prologue: load V tile 0 + E frags tile 0
  float4 vreg[8];
  FragU ef_cur[2], ef_nxt[2];
#pragma unroll
  for (int r = 0; r < 4; ++r) {
    int k2 = vk2 + r * 16;
    vreg[2 * r]     = *(const float4*)(Vb + (size_t)(k2)     * DQ + sc4);
    vreg[2 * r + 1] = *(const float4*)(Vb + (size_t)(k2 + 1) * DQ + sc4);
  }
  ef_cur[0].u = *(const ushort8_t*)(Erow + quad * 8);
  ef_cur[1].u = *(const ushort8_t*)(Erow + 32 + quad * 8);

  bar_lds();   // Li visible to all waves before Linv-folded staging

  // stage tile 0 -> Wt[0]
#pragma unroll
  for (int r = 0; r < 4; ++r) {
    int k2 = vk2 + r * 16;
    float la = Li[k2], lb = Li[k2 + 1];
    float fa[4] = {vreg[2*r].x * la, vreg[2*r].y * la,
                   vreg[2*r].z * la, vreg[2*r].w * la};
    float fb[4] = {vreg[2*r+1].x * lb, vreg[2*r+1].y * lb,
                   vreg[2*r+1].z * lb, vreg[2*r+1].w * lb};
#pragma unroll
    for (int i = 0; i < 4; ++i) {
      int d  = sc4 + i;
      int kk = k2 ^ ((((unsigned)d >> 2) & 7) << 3);   // xor on k-bits 3..5
      *(ushort2*)&Wt[0][d][kk] = make_ushort2(f2bf(fa[i]), f2bf(fb[i]));
    }
  }
  // prefetch tile 1 (V + E) — stays in flight across the loop barrier
#pragma unroll
  for (int r = 0; r < 4; ++r) {
    int k2 = vk2 + r * 16;
    vreg[2 * r]     = *(const float4*)(Vb + (size_t)(64 + k2)     * DQ + sc4);
    vreg[2 * r + 1] = *(const float4*)(Vb + (size_t)(64 + k2 + 1) * DQ + sc4);
  }
  ef_nxt[0].u = *(const ushort8_t*)(Erow + 64 + quad * 8);
  ef_nxt[1].u = *(const ushort8_t*)(Erow + 96 + quad * 8);

  for (int it = 0; it < 32; ++it) {
    const int cur = it & 1;
    bar_lds();  // Wt[cur] writes (iter it-1 / prologue) visible; prev readers
                // of Wt[cur^1] are done -> safe to overwrite below

    // PV MFMA phase: reads ONLY Wt[cur] + ef_cur (no dep on this iter's writes)
#pragma unroll
    for (int c = 0; c < 2; ++c) {
      bf16x8 be = ef_cur[c].b;
#pragma unroll
      for (int j = 0; j < 8; ++j) {
        int d  = 16 * j + l15;
        int kk = (32 * c + quad * 8) ^ ((((unsigned)d >> 2) & 7) << 3);
        bf16x8 aw = ld_frag(&Wt[cur][d][kk]);
        accO[j] = mfma16(aw, be, accO[j]);
      }
    }

    if (it < 31) {
      // stage tile it+1 -> Wt[cur^1] (vreg holds it; Linv folded)
      const int kn = (it + 1) * 64;
#pragma unroll
      for (int r = 0; r < 4; ++r) {
        int k2 = vk2 + r * 16;
        float la = Li[kn + k2], lb = Li[kn + k2 + 1];
        float fa[4] = {vreg[2*r].x * la, vreg[2*r].y * la,
                       vreg[2*r].z * la, vreg[2*r].w * la};
        float fb[4] = {vreg[2*r+1].x * lb, vreg[2*r+1].y * lb,
                       vreg[2*r+1].z * lb, vreg[2*r+1].w * lb};
#pragma unroll
        for (int i = 0; i < 4; ++i) {
          int d  = sc4 + i;
          int kk = k2 ^ ((((unsigned)d >> 2) & 7) << 3);
          *(ushort2*)&Wt[cur ^ 1][d][kk] = make_ushort2(f2bf(fa[i]), f2bf(fb[i]));
        }
      }
      ef_cur[0] = ef_nxt[0];
      ef_cur[1] = ef_nxt[1];
      if (it < 30) {
        // issue global prefetch of tile it+2 (flies across next barrier)
        const int kp = (it + 2) * 64;
#pragma unroll
        for (int r = 0; r < 4; ++r) {
          int k2 = vk2 + r * 16;
          vreg[2 * r]     = *(const float4*)(Vb + (size_t)(kp + k2)     * DQ + sc4);
          vreg[2 * r + 1] = *(const float4*)(Vb + (size_t)(kp + k2 + 1) * DQ + sc4);
        }
        ef_nxt[0].u = *(const ushort8_t*)(Erow + kp + quad * 8);
        ef_nxt[1].u = *(const ushort8_t*)(Erow + kp + 32 + quad * 8);
      }
    }
  }

  // write O: C row = d = 16j+quad*4+r, col = q = q0+16w+l15 -> float4 stores
#pragma unroll
  for (int j = 0; j < 8; ++j) {
    float* op = O + ((size_t)b * SS + q0 + 16 * w + l15) * DQ + 16 * j + quad * 4;
    *(float4*)op = make_float4(accO[j][0], accO[j][1], accO[j][2], accO[j][3]);
  }
}

// ---------------------------------------------------------------------------
// Pass 2 (fallback, no workspace): recompute QK + mask + exp, verified.
// ---------------------------------------------------------------------------
__global__ __launch_bounds__(256, 2) void pass2_out(
    const float* __restrict__ Q, const float* __restrict__ K,
    const float* __restrict__ V, const int* __restrict__ M,
    float* __restrict__ O)
{
  const int b = blockIdx.y, q0 = blockIdx.x * 64;
  const int tid = threadIdx.x;
  const int w = tid >> 6, lane = tid & 63, l15 = lane & 15, quad = lane >> 4;

  __shared__ unsigned short Kbf[64][136];
  __shared__ unsigned short Es[64][72];
  __shared__ unsigned short Wt[128][72];
  __shared__ float Li[SS];

  const float* Qb = Q + (size_t)b * SS * DQ;
  const float* Kb = K + (size_t)b * SS * DQ;
  const float* Vb = V + (size_t)b * SS * DQ;
  const int*   Mb = M + (size_t)b * SS * SS;

  const int srow = tid >> 5;
  const int sc4  = (tid & 31) * 4;

  {
    const float* src = O + ((size_t)b * SS + q0) * DQ;
#pragma unroll
    for (int r = 0; r < 2; ++r) {
      int idx = (tid + r * 256) * 4;
      *(float4*)&Li[idx] = *(const float4*)(src + idx);
    }
  }
  FragU qf[4];
  {
    const float* qrow = Qb + (size_t)(q0 + 16 * w + l15) * DQ;
#pragma unroll
    for (int i = 0; i < 4; ++i) {
      float4 a = *(const float4*)(qrow + 32 * i + quad * 8);
      float4 c = *(const float4*)(qrow + 32 * i + quad * 8 + 4);
      qf[i].u = (ushort8_t){f2bf(a.x), f2bf(a.y), f2bf(a.z), f2bf(a.w),
                            f2bf(c.x), f2bf(c.y), f2bf(c.z), f2bf(c.w)};
    }
  }

  floatx4 accO[8];
#pragma unroll
  for (int j = 0; j < 8; ++j) accO[j] = (floatx4){0.f, 0.f, 0.f, 0.f};

  const int* mrow = Mb + (size_t)(q0 + 16 * w + l15) * SS;

  float4 kreg[8], vreg[8];
  int4 mv_nxt[4];
  const int vk2 = (tid >> 5) * 2;
  {
#pragma unroll
    for (int r = 0; r < 8; ++r)
      kreg[r] = *(const float4*)(Kb + (size_t)(srow + r * 8) * DQ + sc4);
#pragma unroll
    for (int r = 0; r < 4; ++r) {
      int k2 = vk2 + r * 16;
      vreg[2 * r]     = *(const float4*)(Vb + (size_t)(k2)     * DQ + sc4);
      vreg[2 * r + 1] = *(const float4*)(Vb + (size_t)(k2 + 1) * DQ + sc4);
    }
#pragma unroll
    for (int j = 0; j < 4; ++j)
      mv_nxt[j] = *(const int4*)(mrow + 16 * j + quad * 4);
  }

  for (int k0 = 0; k0 < SS; k0 += 64) {
    bar_lds();
    int4 mv[4] = {mv_nxt[0], mv_nxt[1], mv_nxt[2], mv_nxt[3]};

#pragma unroll
    for (int r = 0; r < 8; ++r) {
      float4 v = kreg[r];
      *(ushort4*)&Kbf[srow + r * 8][sc4] =
          make_ushort4(f2bf(v.x), f2bf(v.y), f2bf(v.z), f2bf(v.w));
    }
#pragma unroll
    for (int r = 0; r < 4; ++r) {
      int k2 = vk2 + r * 16;
      float fa[4] = {vreg[2*r].x, vreg[2*r].y, vreg[2*r].z, vreg[2*r].w};
      float fb[4] = {vreg[2*r+1].x, vreg[2*r+1].y, vreg[2*r+1].z, vreg[2*r+1].w};
#pragma unroll
      for (int i = 0; i < 4; ++i) {
        int d  = sc4 + i;
        int kk = k2 ^ ((((unsigned)d >> 2) & 7) << 3);
        *(ushort2*)&Wt[d][kk] = make_ushort2(f2bf(fa[i]), f2bf(fb[i]));
      }
    }
    bar_lds();

    if (k0 + 64 < SS) {
      const int kn = k0 + 64;
#pragma unroll
      for (int r = 0; r < 8; ++r)
        kreg[r] = *(const float4*)(Kb + (size_t)(kn + srow + r * 8) * DQ + sc4);
#pragma unroll
      for (int r = 0; r < 4; ++r) {
        int k2 = vk2 + r * 16;
        vreg[2 * r]     = *(const float4*)(Vb + (size_t)(kn + k2)     * DQ + sc4);
        vreg[2 * r + 1] = *(const float4*)(Vb + (size_t)(kn + k2 + 1) * DQ + sc4);
      }
#pragma unroll
      for (int j = 0; j < 4; ++j)
        mv_nxt[j] = *(const int4*)(mrow + kn + 16 * j + quad * 4);
    }

    floatx4 acc[4];
#pragma unroll
    for (int j = 0; j < 4; ++j) acc[j] = (floatx4){0.f, 0.f, 0.f, 0.f};
#pragma unroll
    for (int i = 0; i < 4; ++i) {
      bf16x8 bq = qf[i].b;
#pragma unroll
      for (int j = 0; j < 4; ++j) {
        bf16x8 ak = ld_frag(&Kbf[16 * j + l15][32 * i + quad * 8]);
        acc[j] = mfma16(ak, bq, acc[j]);
      }
    }
#pragma unroll
    for (int j = 0; j < 4; ++j) {
      float4 liv = *(const float4*)&Li[k0 + 16 * j + quad * 4];
      float lv[4] = {liv.x, liv.y, liv.z, liv.w};
      int mm[4] = {mv[j].x, mv[j].y, mv[j].z, mv[j].w};
      unsigned short es[4];
#pragma unroll
      for (int r = 0; r < 4; ++r) {
        float s = mm[r] ? 1e-9f : acc[j][r] * SCALE;
        es[r] = f2bf(__expf(s) * lv[r]);
      }
      *(ushort4*)&Es[16 * w + l15][16 * j + quad * 4] =
          make_ushort4(es[0], es[1], es[2], es[3]);
    }
#pragma unroll
    for (int c = 0; c < 2; ++c) {
      bf16x8 be = ld_frag(&Es[16 * w + l15][32 * c + quad * 8]);
#pragma unroll
      for (int j = 0; j < 8; ++j) {
        int d  = 16 * j + l15;
        int kk = (32 * c + quad * 8) ^ ((((unsigned)d >> 2) & 7) << 3);
        bf16x8 aw = ld_frag(&Wt[d][kk]);
        accO[j] = mfma16(aw, be, accO[j]);
      }
    }
  }

#pragma unroll
  for (int j = 0; j < 8; ++j) {
    float* op = O + ((size_t)b * SS + q0 + 16 * w + l15) * DQ + 16 * j + quad * 4;
    *(float4*)op = make_float4(accO[j][0], accO[j][1], accO[j][2], accO[j][3]);
  }
}

// ---------------------------------------------------------------------------
extern "C" void kernel_launch(void* const* d_in, const int* in_sizes, int n_in,
                              void* d_out, int out_size, void* d_ws, size_t ws_size,
                              hipStream_t stream) {
  const float* Q = (const float*)d_in[0];
  const float* K = (const float*)d_in[1];
  const float* V = (const float*)d_in[2];
  const int*   M = (const int*)d_in[3];
  float* O = (float*)d_out;

  const size_t eneed = (size_t)NB * SS * SS * sizeof(unsigned short);  // 128 MiB

  zero_accum<<<dim3(NB), 256, 0, stream>>>(O);
  if (d_ws != nullptr && ws_size >= eneed) {
    unsigned short* E = (unsigned short*)d_ws;
    pass1_colsum<1><<<dim3(16, NB, 4), 256, 0, stream>>>(Q, K, M, O, E);
    combine_linv<<<dim3(NB, 8), 256, 0, stream>>>(O);
    pass2_pv<<<dim3(32, NB), 256, 0, stream>>>(V, E, O);
  } else {
    pass1_colsum<0><<<dim3(16, NB, 4), 256, 0, stream>>>(Q, K, M, O, nullptr);
    combine_linv<<<dim3(NB, 8), 256, 0, stream>>>(O);
    pass2_out<<<dim3(32, NB), 256, 0, stream>>>(Q, K, V, M, O);
  }
}